// Round 3
// baseline (304.522 us; speedup 1.0000x reference)
//
#include <hip/hip_runtime.h>
#include <hip/hip_fp16.h>

#define IN_DIM 128
#define HID 64
#define HEADS 4
#define OUT_DIM 40
#define CAP 64
#define NEG 0.2f

__device__ __forceinline__ float lrelu(float v) { return v > 0.f ? v : NEG * v; }

union HU { float2 f2; __half2 h2[2]; };

__device__ __forceinline__ float4 unpack_h4(float2 bits) {
    HU u; u.f2 = bits;
    float2 lo = __half22float2(u.h2[0]);
    float2 hi = __half22float2(u.h2[1]);
    return make_float4(lo.x, lo.y, hi.x, hi.y);
}

// ---------- Kernel A: h0 = relu(x @ Wp + bp) + temb[ts]  [N,64] fp32 ----------
__global__ __launch_bounds__(256) void proj_kernel(
    const float* __restrict__ x, const float* __restrict__ Wp,
    const float* __restrict__ bp, const float* __restrict__ temb,
    const int* __restrict__ ts, float* __restrict__ h0, int N)
{
    __shared__ float Wl[IN_DIM * HID];  // 32 KB
    for (int i = threadIdx.x; i < IN_DIM * HID; i += 256) Wl[i] = Wp[i];
    __syncthreads();

    const int t = threadIdx.x;
    const int lane = t & 63, wq = t >> 6;
    const int cg = lane & 15, ng = lane >> 4;
    const int c0 = cg * 4;
    const int nodeBase = blockIdx.x * 64 + wq * 16 + ng * 4;

    float4 acc[4];
#pragma unroll
    for (int j = 0; j < 4; ++j) acc[j] = make_float4(0.f, 0.f, 0.f, 0.f);

    for (int k0 = 0; k0 < IN_DIM; k0 += 4) {
        float4 xv[4];
#pragma unroll
        for (int j = 0; j < 4; ++j) {
            int n = nodeBase + j; n = n < N ? n : N - 1;
            xv[j] = *(const float4*)(x + (size_t)n * IN_DIM + k0);
        }
        float4 wv[4];
#pragma unroll
        for (int kk = 0; kk < 4; ++kk)
            wv[kk] = *(const float4*)(Wl + (k0 + kk) * HID + c0);
#pragma unroll
        for (int j = 0; j < 4; ++j) {
            const float* xs = (const float*)&xv[j];
#pragma unroll
            for (int kk = 0; kk < 4; ++kk) {
                acc[j].x += xs[kk] * wv[kk].x;
                acc[j].y += xs[kk] * wv[kk].y;
                acc[j].z += xs[kk] * wv[kk].z;
                acc[j].w += xs[kk] * wv[kk].w;
            }
        }
    }
    const float4 bb = *(const float4*)(bp + c0);
#pragma unroll
    for (int j = 0; j < 4; ++j) {
        int n = nodeBase + j;
        if (n < N) {
            int tv = ts[n];
            float4 te = *(const float4*)(temb + (size_t)tv * HID + c0);
            float4 r;
            r.x = fmaxf(acc[j].x + bb.x, 0.f) + te.x;
            r.y = fmaxf(acc[j].y + bb.y, 0.f) + te.y;
            r.z = fmaxf(acc[j].z + bb.z, 0.f) + te.z;
            r.w = fmaxf(acc[j].w + bb.w, 0.f) + te.w;
            *(float4*)(h0 + (size_t)n * HID + c0) = r;
        }
    }
}

// ---------- Kernel B: h = h0 @ Wg -> fp16; a_src/a_dst head dots ----------
// Wg staged fp16 (32 KB LDS -> 5 blocks/CU). 32 nodes/block, 8 nodes/wave.
__global__ __launch_bounds__(256) void gatproj_kernel(
    const float* __restrict__ h0, const float* __restrict__ Wg,
    const float* __restrict__ attS, const float* __restrict__ attD,
    __half* __restrict__ hh, float* __restrict__ aS, float* __restrict__ aD, int N)
{
    __shared__ __half Wl[HID * 256];  // 32 KB fp16
    for (int i = threadIdx.x * 4; i < HID * 256; i += 256 * 4) {
        float4 w = *(const float4*)(Wg + i);
        HU u;
        u.h2[0] = __floats2half2_rn(w.x, w.y);
        u.h2[1] = __floats2half2_rn(w.z, w.w);
        *(float2*)(Wl + i) = u.f2;
    }
    __syncthreads();

    const int t = threadIdx.x;
    const int lane = t & 63, wq = t >> 6;
    const int c0 = lane * 4;
    const int nodeBase = blockIdx.x * 32 + wq * 8;

    float4 acc[8];
#pragma unroll
    for (int j = 0; j < 8; ++j) acc[j] = make_float4(0.f, 0.f, 0.f, 0.f);

    for (int k0 = 0; k0 < HID; k0 += 4) {
        float4 xv[8];
#pragma unroll
        for (int j = 0; j < 8; ++j) {
            int n = nodeBase + j; n = n < N ? n : N - 1;
            xv[j] = *(const float4*)(h0 + (size_t)n * HID + k0);
        }
        float4 wv[4];
#pragma unroll
        for (int kk = 0; kk < 4; ++kk)
            wv[kk] = unpack_h4(*(const float2*)(Wl + (k0 + kk) * 256 + c0));
#pragma unroll
        for (int j = 0; j < 8; ++j) {
            const float* xs = (const float*)&xv[j];
#pragma unroll
            for (int kk = 0; kk < 4; ++kk) {
                acc[j].x += xs[kk] * wv[kk].x;
                acc[j].y += xs[kk] * wv[kk].y;
                acc[j].z += xs[kk] * wv[kk].z;
                acc[j].w += xs[kk] * wv[kk].w;
            }
        }
    }
    const float4 s4 = *(const float4*)(attS + c0);
    const float4 d4 = *(const float4*)(attD + c0);
#pragma unroll
    for (int j = 0; j < 8; ++j) {
        int n = nodeBase + j;
        float ps = acc[j].x * s4.x + acc[j].y * s4.y + acc[j].z * s4.z + acc[j].w * s4.w;
        float pd = acc[j].x * d4.x + acc[j].y * d4.y + acc[j].z * d4.z + acc[j].w * d4.w;
#pragma unroll
        for (int off = 8; off > 0; off >>= 1) {
            ps += __shfl_down(ps, off);
            pd += __shfl_down(pd, off);
        }
        if (n < N) {
            HU u;
            u.h2[0] = __floats2half2_rn(acc[j].x, acc[j].y);
            u.h2[1] = __floats2half2_rn(acc[j].z, acc[j].w);
            *(float2*)(hh + (size_t)n * 256 + c0) = u.f2;
            if ((lane & 15) == 0) {
                int hd = lane >> 4;
                aS[n * 4 + hd] = ps;
                aD[n * 4 + hd] = pd;
            }
        }
    }
}

// ---------- CSR build: bucket edges by dst ----------
__global__ void fill_kernel(const int* __restrict__ ei, int E,
                            int* __restrict__ deg, int* __restrict__ csr)
{
    int e = (blockIdx.x * 256 + threadIdx.x) * 2;
    if (e >= E) return;
    int2 s2 = *(const int2*)(ei + e);
    int2 d2 = *(const int2*)(ei + E + e);
    int slot0 = atomicAdd(&deg[d2.x], 1);
    if (slot0 < CAP) csr[(size_t)d2.x * CAP + slot0] = s2.x;
    int slot1 = atomicAdd(&deg[d2.y], 1);
    if (slot1 < CAP) csr[(size_t)d2.y * CAP + slot1] = s2.y;
}

// ---------- Kernel D: per-dst TWO-PASS softmax aggregation -> gat fp16 ----------
__global__ __launch_bounds__(256) void agg_kernel(
    const __half* __restrict__ hh, const float* __restrict__ aS,
    const float* __restrict__ aD, const int* __restrict__ deg,
    const int* __restrict__ csr, const float* __restrict__ bg,
    __half* __restrict__ gat, int N)
{
    __shared__ float e_lds[4 * CAP * HEADS];  // 4 KB
    __shared__ int   s_lds[4 * CAP];          // 1 KB

    const int t = threadIdx.x;
    const int lane = t & 63, wq = t >> 6;
    const int n = blockIdx.x * 4 + wq;
    if (n >= N) return;
    const int hd = lane >> 4, li = lane & 15;
    const int c0 = lane * 4;

    const float adn = aD[n * 4 + hd];
    const float es = lrelu(aS[n * 4 + hd] + adn);  // self-loop score

    int dn = deg[n]; dn = dn < CAP ? dn : CAP;
    const int* cs = csr + (size_t)n * CAP;
    float* eL = e_lds + wq * CAP * HEADS;
    int*   sL = s_lds + wq * CAP;

    // ---- pass 1: per-lane online (m,s), 16-way edge parallel per head ----
    float m = -1e30f, s = 0.f;
    for (int i = li; i < dn; i += 16) {
        int src = cs[i];
        if (hd == 0) sL[i] = src;
        float e = lrelu(aS[src * 4 + hd] + adn);
        eL[i * HEADS + hd] = e;
        float mn = fmaxf(m, e);
        s = s * __expf(m - mn) + __expf(e - mn);
        m = mn;
    }
#pragma unroll
    for (int off = 8; off > 0; off >>= 1) {
        float om = __shfl_xor(m, off);
        float os = __shfl_xor(s, off);
        float mn = fmaxf(m, om);
        s = s * __expf(m - mn) + os * __expf(om - mn);
        m = mn;
    }
    {
        float mn = fmaxf(m, es);
        s = s * __expf(m - mn) + __expf(es - mn);
        m = mn;
    }

    // ---- pass 2: acc = sum p_i * h[src_i], 8 rows in flight ----
    float4 a0 = make_float4(0.f, 0.f, 0.f, 0.f), a1 = a0, a2 = a0, a3 = a0;
    {
        float p = __expf(es - m);
        float4 hv = unpack_h4(*(const float2*)(hh + (size_t)n * 256 + c0));
        a0.x = p * hv.x; a0.y = p * hv.y; a0.z = p * hv.z; a0.w = p * hv.w;
    }
    int i = 0;
    for (; i + 8 <= dn; i += 8) {
        int4 sa = *(const int4*)(sL + i);
        int4 sb = *(const int4*)(sL + i + 4);
        int ss[8] = { sa.x, sa.y, sa.z, sa.w, sb.x, sb.y, sb.z, sb.w };
        float2 bits[8];
#pragma unroll
        for (int r = 0; r < 8; ++r)
            bits[r] = *(const float2*)(hh + (size_t)ss[r] * 256 + c0);
        float p[8];
#pragma unroll
        for (int r = 0; r < 8; ++r)
            p[r] = __expf(eL[(i + r) * HEADS + hd] - m);
#pragma unroll
        for (int r = 0; r < 8; ++r) {
            float4 hv = unpack_h4(bits[r]);
            float4* ap = (r & 3) == 0 ? &a0 : (r & 3) == 1 ? &a1 : (r & 3) == 2 ? &a2 : &a3;
            ap->x += p[r] * hv.x; ap->y += p[r] * hv.y;
            ap->z += p[r] * hv.z; ap->w += p[r] * hv.w;
        }
    }
    for (; i + 4 <= dn; i += 4) {
        int4 sa = *(const int4*)(sL + i);
        int ss[4] = { sa.x, sa.y, sa.z, sa.w };
        float2 bits[4];
#pragma unroll
        for (int r = 0; r < 4; ++r)
            bits[r] = *(const float2*)(hh + (size_t)ss[r] * 256 + c0);
        float p[4];
#pragma unroll
        for (int r = 0; r < 4; ++r)
            p[r] = __expf(eL[(i + r) * HEADS + hd] - m);
#pragma unroll
        for (int r = 0; r < 4; ++r) {
            float4 hv = unpack_h4(bits[r]);
            float4* ap = r == 0 ? &a0 : r == 1 ? &a1 : r == 2 ? &a2 : &a3;
            ap->x += p[r] * hv.x; ap->y += p[r] * hv.y;
            ap->z += p[r] * hv.z; ap->w += p[r] * hv.w;
        }
    }
    for (; i < dn; ++i) {
        int s0 = sL[i];
        float p = __expf(eL[i * HEADS + hd] - m);
        float4 hv = unpack_h4(*(const float2*)(hh + (size_t)s0 * 256 + c0));
        a0.x += p * hv.x; a0.y += p * hv.y; a0.z += p * hv.z; a0.w += p * hv.w;
    }
    float4 acc;
    acc.x = (a0.x + a1.x) + (a2.x + a3.x);
    acc.y = (a0.y + a1.y) + (a2.y + a3.y);
    acc.z = (a0.z + a1.z) + (a2.z + a3.z);
    acc.w = (a0.w + a1.w) + (a2.w + a3.w);

    const float inv = 1.f / (s + 1e-16f);
    const float4 b4 = *(const float4*)(bg + c0);
    HU g;
    g.h2[0] = __floats2half2_rn(fmaxf(acc.x * inv + b4.x, 0.f),
                                fmaxf(acc.y * inv + b4.y, 0.f));
    g.h2[1] = __floats2half2_rn(fmaxf(acc.z * inv + b4.z, 0.f),
                                fmaxf(acc.w * inv + b4.w, 0.f));
    *(float2*)(gat + (size_t)n * 256 + c0) = g.f2;
}

// ---------- Kernel E: out = gat(fp16) @ Wc + bc  [N,40] ----------
__global__ __launch_bounds__(256) void cls_kernel(
    const __half* __restrict__ gat, const float* __restrict__ Wc,
    const float* __restrict__ bc, float* __restrict__ out, int N)
{
    __shared__ float Wl[256 * OUT_DIM];  // 40 KB
    for (int i = threadIdx.x; i < 256 * OUT_DIM; i += 256) Wl[i] = Wc[i];
    __syncthreads();

    const int t = threadIdx.x;
    const int lane = t & 63, wq = t >> 6;
    const int cg = lane % 10, ng = lane / 10;
    const int c0 = cg * 4;
    const bool live = ng < 6;
    const int nodeBase = blockIdx.x * 96 + wq * 24 + ng * 4;

    float4 acc[4];
#pragma unroll
    for (int j = 0; j < 4; ++j) acc[j] = make_float4(0.f, 0.f, 0.f, 0.f);

    for (int k0 = 0; k0 < 256; k0 += 4) {
        float4 xv[4];
#pragma unroll
        for (int j = 0; j < 4; ++j) {
            int n = nodeBase + j;
            n = (live && n < N) ? n : 0;
            xv[j] = unpack_h4(*(const float2*)(gat + (size_t)n * 256 + k0));
        }
        float4 wv[4];
#pragma unroll
        for (int kk = 0; kk < 4; ++kk)
            wv[kk] = *(const float4*)(Wl + (k0 + kk) * OUT_DIM + c0);
#pragma unroll
        for (int j = 0; j < 4; ++j) {
            const float* xs = (const float*)&xv[j];
#pragma unroll
            for (int kk = 0; kk < 4; ++kk) {
                acc[j].x += xs[kk] * wv[kk].x;
                acc[j].y += xs[kk] * wv[kk].y;
                acc[j].z += xs[kk] * wv[kk].z;
                acc[j].w += xs[kk] * wv[kk].w;
            }
        }
    }
    const float4 b4 = *(const float4*)(bc + c0);
#pragma unroll
    for (int j = 0; j < 4; ++j) {
        int n = nodeBase + j;
        if (live && n < N) {
            float4 r;
            r.x = acc[j].x + b4.x;
            r.y = acc[j].y + b4.y;
            r.z = acc[j].z + b4.z;
            r.w = acc[j].w + b4.w;
            *(float4*)(out + (size_t)n * OUT_DIM + c0) = r;
        }
    }
}

extern "C" void kernel_launch(void* const* d_in, const int* in_sizes, int n_in,
                              void* d_out, int out_size, void* d_ws, size_t ws_size,
                              hipStream_t stream) {
    const float* x    = (const float*)d_in[0];
    const int*   ei   = (const int*)d_in[1];
    const int*   ts   = (const int*)d_in[2];
    const float* Wp   = (const float*)d_in[3];
    const float* bp   = (const float*)d_in[4];
    const float* temb = (const float*)d_in[5];
    const float* Wg   = (const float*)d_in[6];
    const float* attS = (const float*)d_in[7];
    const float* attD = (const float*)d_in[8];
    const float* bg   = (const float*)d_in[9];
    const float* Wc   = (const float*)d_in[10];
    const float* bc   = (const float*)d_in[11];
    float* out = (float*)d_out;

    const int N = in_sizes[0] / IN_DIM;   // 50000
    const int E = in_sizes[1] / 2;        // 800000

    char* w = (char*)d_ws;
    float*  h0   = (float*)w;  w += (size_t)N * HID * 4;
    __half* hh   = (__half*)w; w += (size_t)N * 256 * 2;
    __half* gat  = (__half*)w; w += (size_t)N * 256 * 2;
    float*  aS   = (float*)w;  w += (size_t)N * HEADS * 4;
    float*  aD   = (float*)w;  w += (size_t)N * HEADS * 4;
    int*    deg  = (int*)w;    w += (size_t)N * 4;
    int*    csr  = (int*)w;    w += (size_t)N * CAP * 4;

    hipMemsetAsync(deg, 0, (size_t)N * 4, stream);
    fill_kernel<<<(E / 2 + 255) / 256, 256, 0, stream>>>(ei, E, deg, csr);
    proj_kernel<<<(N + 63) / 64, 256, 0, stream>>>(x, Wp, bp, temb, ts, h0, N);
    gatproj_kernel<<<(N + 31) / 32, 256, 0, stream>>>(h0, Wg, attS, attD, hh, aS, aD, N);
    agg_kernel<<<(N + 3) / 4, 256, 0, stream>>>(hh, aS, aD, deg, csr, bg, gat, N);
    cls_kernel<<<(N + 95) / 96, 256, 0, stream>>>(gat, Wc, bc, out, N);
}

// Round 5
// 297.967 us; speedup vs baseline: 1.0220x; 1.0220x over previous
//
#include <hip/hip_runtime.h>
#include <hip/hip_fp16.h>

#define IN_DIM 128
#define HID 64
#define HEADS 4
#define OUT_DIM 40
#define CAP 64
#define NEG 0.2f

__device__ __forceinline__ float lrelu(float v) { return v > 0.f ? v : NEG * v; }

union HU { float2 f2; __half2 h2[2]; };

__device__ __forceinline__ float4 unpack_h4(float2 bits) {
    HU u; u.f2 = bits;
    float2 lo = __half22float2(u.h2[0]);
    float2 hi = __half22float2(u.h2[1]);
    return make_float4(lo.x, lo.y, hi.x, hi.y);
}

// ---------- Kernel A: h0 = relu(x@Wp+bp)+temb[ts] -> fp16 [N,64]
//            + fused aS/aD via folded logits attX'[k][hd] = sum_c Wg[k][hd*64+c]*attX[hd][c]
__global__ __launch_bounds__(256) void proj_kernel(
    const float* __restrict__ x, const float* __restrict__ Wp,
    const float* __restrict__ bp, const float* __restrict__ temb,
    const int* __restrict__ ts, const float* __restrict__ Wg,
    const float* __restrict__ attS, const float* __restrict__ attD,
    __half* __restrict__ h0h, float* __restrict__ aS, float* __restrict__ aD, int N)
{
    __shared__ float Wl[IN_DIM * HID];   // 32 KB
    __shared__ float As[HID * HEADS];    // 1 KB
    __shared__ float Ad[HID * HEADS];    // 1 KB
    for (int i = threadIdx.x; i < IN_DIM * HID; i += 256) Wl[i] = Wp[i];
    {
        int k = threadIdx.x >> 2, hd = threadIdx.x & 3;
        const float* wr = Wg + k * 256 + hd * 64;
        const float* as = attS + hd * 64;
        const float* ad = attD + hd * 64;
        float ss = 0.f, dd = 0.f;
        for (int c = 0; c < 64; ++c) { float w = wr[c]; ss += w * as[c]; dd += w * ad[c]; }
        As[k * 4 + hd] = ss;
        Ad[k * 4 + hd] = dd;
    }
    __syncthreads();

    const int t = threadIdx.x;
    const int lane = t & 63, wq = t >> 6;
    const int cg = lane & 15, ng = lane >> 4;
    const int c0 = cg * 4;
    const int nodeBase = blockIdx.x * 64 + wq * 16 + ng * 4;

    float4 acc[4];
#pragma unroll
    for (int j = 0; j < 4; ++j) acc[j] = make_float4(0.f, 0.f, 0.f, 0.f);

    for (int k0 = 0; k0 < IN_DIM; k0 += 4) {
        float4 xv[4];
#pragma unroll
        for (int j = 0; j < 4; ++j) {
            int n = nodeBase + j; n = n < N ? n : N - 1;
            xv[j] = *(const float4*)(x + (size_t)n * IN_DIM + k0);
        }
        float4 wv[4];
#pragma unroll
        for (int kk = 0; kk < 4; ++kk)
            wv[kk] = *(const float4*)(Wl + (k0 + kk) * HID + c0);
#pragma unroll
        for (int j = 0; j < 4; ++j) {
            const float* xs = (const float*)&xv[j];
#pragma unroll
            for (int kk = 0; kk < 4; ++kk) {
                acc[j].x += xs[kk] * wv[kk].x;
                acc[j].y += xs[kk] * wv[kk].y;
                acc[j].z += xs[kk] * wv[kk].z;
                acc[j].w += xs[kk] * wv[kk].w;
            }
        }
    }
    const float4 bb = *(const float4*)(bp + c0);
    const float4* As4 = (const float4*)As;  // As4[k] = 4 heads of channel k
    const float4* Ad4 = (const float4*)Ad;
#pragma unroll
    for (int j = 0; j < 4; ++j) {
        int n = nodeBase + j;
        float4 r = make_float4(0.f, 0.f, 0.f, 0.f);
        if (n < N) {
            int tv = ts[n];
            float4 te = *(const float4*)(temb + (size_t)tv * HID + c0);
            r.x = fmaxf(acc[j].x + bb.x, 0.f) + te.x;
            r.y = fmaxf(acc[j].y + bb.y, 0.f) + te.y;
            r.z = fmaxf(acc[j].z + bb.z, 0.f) + te.z;
            r.w = fmaxf(acc[j].w + bb.w, 0.f) + te.w;
            HU u;
            u.h2[0] = __floats2half2_rn(r.x, r.y);
            u.h2[1] = __floats2half2_rn(r.z, r.w);
            *(float2*)(h0h + (size_t)n * HID + c0) = u.f2;
        }
        float4 s0 = As4[c0], s1 = As4[c0 + 1], s2 = As4[c0 + 2], s3 = As4[c0 + 3];
        float4 d0 = Ad4[c0], d1 = Ad4[c0 + 1], d2 = Ad4[c0 + 2], d3 = Ad4[c0 + 3];
        float4 pS, pD;
        pS.x = r.x * s0.x + r.y * s1.x + r.z * s2.x + r.w * s3.x;
        pS.y = r.x * s0.y + r.y * s1.y + r.z * s2.y + r.w * s3.y;
        pS.z = r.x * s0.z + r.y * s1.z + r.z * s2.z + r.w * s3.z;
        pS.w = r.x * s0.w + r.y * s1.w + r.z * s2.w + r.w * s3.w;
        pD.x = r.x * d0.x + r.y * d1.x + r.z * d2.x + r.w * d3.x;
        pD.y = r.x * d0.y + r.y * d1.y + r.z * d2.y + r.w * d3.y;
        pD.z = r.x * d0.z + r.y * d1.z + r.z * d2.z + r.w * d3.z;
        pD.w = r.x * d0.w + r.y * d1.w + r.z * d2.w + r.w * d3.w;
#pragma unroll
        for (int off = 8; off > 0; off >>= 1) {
            pS.x += __shfl_down(pS.x, off); pS.y += __shfl_down(pS.y, off);
            pS.z += __shfl_down(pS.z, off); pS.w += __shfl_down(pS.w, off);
            pD.x += __shfl_down(pD.x, off); pD.y += __shfl_down(pD.y, off);
            pD.z += __shfl_down(pD.z, off); pD.w += __shfl_down(pD.w, off);
        }
        if (cg == 0 && n < N) {
            *(float4*)(aS + (size_t)n * 4) = pS;
            *(float4*)(aD + (size_t)n * 4) = pD;
        }
    }
}

// ---------- CSR build ----------
__global__ void fill_kernel(const int* __restrict__ ei, int E,
                            int* __restrict__ deg, int* __restrict__ csr)
{
    int e = (blockIdx.x * 256 + threadIdx.x) * 4;
    if (e >= E) return;
    int4 s4 = *(const int4*)(ei + e);
    int4 d4 = *(const int4*)(ei + E + e);
    int sl;
    sl = atomicAdd(&deg[d4.x], 1); if (sl < CAP) csr[(size_t)d4.x * CAP + sl] = s4.x;
    sl = atomicAdd(&deg[d4.y], 1); if (sl < CAP) csr[(size_t)d4.y * CAP + sl] = s4.y;
    sl = atomicAdd(&deg[d4.z], 1); if (sl < CAP) csr[(size_t)d4.z * CAP + sl] = s4.z;
    sl = atomicAdd(&deg[d4.w], 1); if (sl < CAP) csr[(size_t)d4.w * CAP + sl] = s4.w;
}

// ---------- Kernel D: agg0[n,hd,k] = (sum_i p_i,hd * h0[src_i,k]) / s_hd  -> fp16 [N,4,64]
// one wave per dst node; lane = h0 channel; 4 head-accumulators per lane.
__global__ __launch_bounds__(256) void agg_kernel(
    const __half* __restrict__ h0h, const float* __restrict__ aS,
    const float* __restrict__ aD, const int* __restrict__ deg,
    const int* __restrict__ csr, __half* __restrict__ agg0h, int N)
{
    __shared__ float p_lds[4 * CAP * HEADS];  // 4 KB: e then p, [CAP][4] per wave
    __shared__ int   s_lds[4 * CAP];          // 1 KB

    const int t = threadIdx.x;
    const int lane = t & 63, wq = t >> 6;
    const int n = blockIdx.x * 4 + wq;
    if (n >= N) return;
    const int hd16 = lane >> 4, li = lane & 15;

    const float adn = aD[n * 4 + hd16];
    const float es = lrelu(aS[n * 4 + hd16] + adn);  // self-loop score (head hd16)

    int dn = deg[n]; dn = dn < CAP ? dn : CAP;
    const int* cs = csr + (size_t)n * CAP;
    float* pL = p_lds + wq * CAP * HEADS;
    int*   sL = s_lds + wq * CAP;

    // ---- pass 1: per-lane online (m,s), 16-way edge parallel per head ----
    float m = -1e30f, s = 0.f;
    for (int i = li; i < dn; i += 16) {
        int src = cs[i];
        if (hd16 == 0) sL[i] = src;
        float e = lrelu(aS[src * 4 + hd16] + adn);
        pL[i * HEADS + hd16] = e;  // store raw e for now
        float mn = fmaxf(m, e);
        s = s * __expf(m - mn) + __expf(e - mn);
        m = mn;
    }
#pragma unroll
    for (int off = 8; off > 0; off >>= 1) {
        float om = __shfl_xor(m, off);
        float os = __shfl_xor(s, off);
        float mn = fmaxf(m, om);
        s = s * __expf(m - mn) + os * __expf(om - mn);
        m = mn;
    }
    {
        float mn = fmaxf(m, es);
        s = s * __expf(m - mn) + __expf(es - mn);
        m = mn;
    }
    // broadcast per-head m / inv / p_self to every lane
    float inv = 1.f / (s + 1e-16f);
    float pself = __expf(es - m);
    float mh[4], invh[4], pselfh[4];
#pragma unroll
    for (int h = 0; h < 4; ++h) {
        mh[h]     = __shfl(m, h * 16);
        invh[h]   = __shfl(inv, h * 16);
        pselfh[h] = __shfl(pself, h * 16);
    }
    // convert e -> p in LDS (amortized exp)
    for (int idx = lane; idx < dn * 4; idx += 64)
        pL[idx] = __expf(pL[idx] - mh[idx & 3]);

    // ---- pass 2: lane = channel; gather 128B h0 rows, 4 head-accumulators ----
    float a0, a1, a2, a3;
    {
        float v = __half2float(h0h[(size_t)n * HID + lane]);
        a0 = pselfh[0] * v; a1 = pselfh[1] * v;
        a2 = pselfh[2] * v; a3 = pselfh[3] * v;
    }
    int i = 0;
    for (; i + 8 <= dn; i += 8) {
        int4 sa = *(const int4*)(sL + i);
        int4 sb = *(const int4*)(sL + i + 4);
        int ss[8] = { sa.x, sa.y, sa.z, sa.w, sb.x, sb.y, sb.z, sb.w };
        __half hv[8];
#pragma unroll
        for (int r = 0; r < 8; ++r)
            hv[r] = h0h[(size_t)ss[r] * HID + lane];
#pragma unroll
        for (int r = 0; r < 8; ++r) {
            float4 p4 = *(const float4*)(pL + (i + r) * 4);  // broadcast
            float v = __half2float(hv[r]);
            a0 += p4.x * v; a1 += p4.y * v; a2 += p4.z * v; a3 += p4.w * v;
        }
    }
    for (; i < dn; ++i) {
        int s0 = sL[i];
        float4 p4 = *(const float4*)(pL + i * 4);
        float v = __half2float(h0h[(size_t)s0 * HID + lane]);
        a0 += p4.x * v; a1 += p4.y * v; a2 += p4.z * v; a3 += p4.w * v;
    }
    __half* dst = agg0h + (size_t)n * 256;
    dst[0 * 64 + lane] = __float2half(a0 * invh[0]);
    dst[1 * 64 + lane] = __float2half(a1 * invh[1]);
    dst[2 * 64 + lane] = __float2half(a2 * invh[2]);
    dst[3 * 64 + lane] = __float2half(a3 * invh[3]);
}

// ---------- Kernel B2: gat[n,o] = relu(sum_k agg0[n, o/64, k] * Wg[k,o] + bg[o]) -> fp16
__global__ __launch_bounds__(256) void gatproj_kernel(
    const __half* __restrict__ agg0h, const float* __restrict__ Wg,
    const float* __restrict__ bg, __half* __restrict__ gat, int N)
{
    __shared__ __half Wl[HID * 256];  // 32 KB fp16
    for (int i = threadIdx.x * 4; i < HID * 256; i += 256 * 4) {
        float4 w = *(const float4*)(Wg + i);
        HU u;
        u.h2[0] = __floats2half2_rn(w.x, w.y);
        u.h2[1] = __floats2half2_rn(w.z, w.w);
        *(float2*)(Wl + i) = u.f2;
    }
    __syncthreads();

    const int t = threadIdx.x;
    const int lane = t & 63, wq = t >> 6;
    const int c0 = lane * 4;
    const int headBase = (c0 >> 6) << 6;  // hd*64
    const int nodeBase = blockIdx.x * 32 + wq * 8;

    float4 acc[8];
#pragma unroll
    for (int j = 0; j < 8; ++j) acc[j] = make_float4(0.f, 0.f, 0.f, 0.f);

    for (int k0 = 0; k0 < HID; k0 += 4) {
        float4 xv[8];
#pragma unroll
        for (int j = 0; j < 8; ++j) {
            int n = nodeBase + j; n = n < N ? n : N - 1;
            xv[j] = unpack_h4(*(const float2*)(agg0h + (size_t)n * 256 + headBase + k0));
        }
        float4 wv[4];
#pragma unroll
        for (int kk = 0; kk < 4; ++kk)
            wv[kk] = unpack_h4(*(const float2*)(Wl + (k0 + kk) * 256 + c0));
#pragma unroll
        for (int j = 0; j < 8; ++j) {
            const float* xs = (const float*)&xv[j];
#pragma unroll
            for (int kk = 0; kk < 4; ++kk) {
                acc[j].x += xs[kk] * wv[kk].x;
                acc[j].y += xs[kk] * wv[kk].y;
                acc[j].z += xs[kk] * wv[kk].z;
                acc[j].w += xs[kk] * wv[kk].w;
            }
        }
    }
    const float4 b4 = *(const float4*)(bg + c0);
#pragma unroll
    for (int j = 0; j < 8; ++j) {
        int n = nodeBase + j;
        if (n < N) {
            HU u;
            u.h2[0] = __floats2half2_rn(fmaxf(acc[j].x + b4.x, 0.f),
                                        fmaxf(acc[j].y + b4.y, 0.f));
            u.h2[1] = __floats2half2_rn(fmaxf(acc[j].z + b4.z, 0.f),
                                        fmaxf(acc[j].w + b4.w, 0.f));
            *(float2*)(gat + (size_t)n * 256 + c0) = u.f2;
        }
    }
}

// ---------- Kernel E: out = gat(fp16) @ Wc + bc  [N,40] ----------
__global__ __launch_bounds__(256) void cls_kernel(
    const __half* __restrict__ gat, const float* __restrict__ Wc,
    const float* __restrict__ bc, float* __restrict__ out, int N)
{
    __shared__ float Wl[256 * OUT_DIM];  // 40 KB
    for (int i = threadIdx.x; i < 256 * OUT_DIM; i += 256) Wl[i] = Wc[i];
    __syncthreads();

    const int t = threadIdx.x;
    const int lane = t & 63, wq = t >> 6;
    const int cg = lane % 10, ng = lane / 10;
    const int c0 = cg * 4;
    const bool live = ng < 6;
    const int nodeBase = blockIdx.x * 96 + wq * 24 + ng * 4;

    float4 acc[4];
#pragma unroll
    for (int j = 0; j < 4; ++j) acc[j] = make_float4(0.f, 0.f, 0.f, 0.f);

    for (int k0 = 0; k0 < 256; k0 += 4) {
        float4 xv[4];
#pragma unroll
        for (int j = 0; j < 4; ++j) {
            int n = nodeBase + j;
            n = (live && n < N) ? n : 0;
            xv[j] = unpack_h4(*(const float2*)(gat + (size_t)n * 256 + k0));
        }
        float4 wv[4];
#pragma unroll
        for (int kk = 0; kk < 4; ++kk)
            wv[kk] = *(const float4*)(Wl + (k0 + kk) * OUT_DIM + c0);
#pragma unroll
        for (int j = 0; j < 4; ++j) {
            const float* xs = (const float*)&xv[j];
#pragma unroll
            for (int kk = 0; kk < 4; ++kk) {
                acc[j].x += xs[kk] * wv[kk].x;
                acc[j].y += xs[kk] * wv[kk].y;
                acc[j].z += xs[kk] * wv[kk].z;
                acc[j].w += xs[kk] * wv[kk].w;
            }
        }
    }
    const float4 b4 = *(const float4*)(bc + c0);
#pragma unroll
    for (int j = 0; j < 4; ++j) {
        int n = nodeBase + j;
        if (live && n < N) {
            float4 r;
            r.x = acc[j].x + b4.x;
            r.y = acc[j].y + b4.y;
            r.z = acc[j].z + b4.z;
            r.w = acc[j].w + b4.w;
            *(float4*)(out + (size_t)n * OUT_DIM + c0) = r;
        }
    }
}

extern "C" void kernel_launch(void* const* d_in, const int* in_sizes, int n_in,
                              void* d_out, int out_size, void* d_ws, size_t ws_size,
                              hipStream_t stream) {
    const float* x    = (const float*)d_in[0];
    const int*   ei   = (const int*)d_in[1];
    const int*   ts   = (const int*)d_in[2];
    const float* Wp   = (const float*)d_in[3];
    const float* bp   = (const float*)d_in[4];
    const float* temb = (const float*)d_in[5];
    const float* Wg   = (const float*)d_in[6];
    const float* attS = (const float*)d_in[7];
    const float* attD = (const float*)d_in[8];
    const float* bg   = (const float*)d_in[9];
    const float* Wc   = (const float*)d_in[10];
    const float* bc   = (const float*)d_in[11];
    float* out = (float*)d_out;

    const int N = in_sizes[0] / IN_DIM;   // 50000
    const int E = in_sizes[1] / 2;        // 800000

    char* w = (char*)d_ws;
    __half* h0h   = (__half*)w; w += (size_t)N * HID * 2;
    __half* agg0h = (__half*)w; w += (size_t)N * 256 * 2;
    __half* gat   = (__half*)w; w += (size_t)N * 256 * 2;
    float*  aS    = (float*)w;  w += (size_t)N * HEADS * 4;
    float*  aD    = (float*)w;  w += (size_t)N * HEADS * 4;
    int*    deg   = (int*)w;    w += (size_t)N * 4;
    int*    csr   = (int*)w;    w += (size_t)N * CAP * 4;

    hipMemsetAsync(deg, 0, (size_t)N * 4, stream);
    fill_kernel<<<(E / 4 + 255) / 256, 256, 0, stream>>>(ei, E, deg, csr);
    proj_kernel<<<(N + 63) / 64, 256, 0, stream>>>(x, Wp, bp, temb, ts, Wg, attS, attD,
                                                   h0h, aS, aD, N);
    agg_kernel<<<(N + 3) / 4, 256, 0, stream>>>(h0h, aS, aD, deg, csr, agg0h, N);
    gatproj_kernel<<<(N + 31) / 32, 256, 0, stream>>>(agg0h, Wg, bg, gat, N);
    cls_kernel<<<(N + 95) / 96, 256, 0, stream>>>(gat, Wc, bc, out, N);
}